// Round 8
// baseline (918.986 us; speedup 1.0000x reference)
//
#include <hip/hip_runtime.h>
#include <cstdint>
#include <cstddef>

#define SEQ   2048
#define NH    16
#define DKD   64
#define DM    1024

typedef __attribute__((ext_vector_type(8))) short bf16x8;
typedef __attribute__((ext_vector_type(4))) short bf16x4;
typedef __attribute__((ext_vector_type(4))) float f32x4;
typedef unsigned short u16;

__device__ __forceinline__ u16 f2bf(float f) {
    union { float f; unsigned u; } v; v.f = f;
    unsigned r = v.u + 0x7fff + ((v.u >> 16) & 1);   // RNE
    return (u16)(r >> 16);
}
__device__ __forceinline__ float bf2f(u16 b) {
    union { unsigned u; float f; } v; v.u = ((unsigned)b) << 16;
    return v.f;
}
// raw ISA transcendentals (glibc macro collision avoids __exp2f/__log2f):
__device__ __forceinline__ float exp2_hw(float x) { return __builtin_amdgcn_exp2f(x); }
__device__ __forceinline__ float log2_hw(float x) { return __builtin_amdgcn_logf(x); }

// async global->LDS, 16B per lane. LDS dest = wave-uniform base + lane*16.
__device__ __forceinline__ void gload16(const void* g, void* l) {
    __builtin_amdgcn_global_load_lds(
        (const __attribute__((address_space(1))) void*)g,
        (__attribute__((address_space(3))) void*)l, 16, 0, 0);
}

// ---------------------------------------------------------------------------
// One-shot fp32 -> bf16 cast of q,k,v and wq,wk,wv,wo (into wb). RNE.
// ---------------------------------------------------------------------------
__global__ __launch_bounds__(256)
void cast_all(const float* __restrict__ q, const float* __restrict__ k,
              const float* __restrict__ v, const float* __restrict__ wq,
              const float* __restrict__ wk, const float* __restrict__ wv,
              const float* __restrict__ wo,
              u16* __restrict__ qb, u16* __restrict__ kb, u16* __restrict__ vb,
              u16* __restrict__ wb) {
    const int z = blockIdx.y;
    const float* s;
    u16* d;
    if (z < 12) {
        int a = z >> 2;
        s = (a == 0 ? q : a == 1 ? k : v) + (size_t)(z & 3) * 1048576;
        d = (a == 0 ? qb : a == 1 ? kb : vb) + (size_t)(z & 3) * 1048576;
    } else {
        int a = z - 12;
        s = (a == 0 ? wq : a == 1 ? wk : a == 2 ? wv : wo);
        d = wb + (size_t)a * 1048576;
    }
    size_t i = ((size_t)blockIdx.x * 256 + threadIdx.x) * 8;
    f32x4 x0 = *(const f32x4*)&s[i];
    f32x4 x1 = *(const f32x4*)&s[i + 4];
    bf16x8 o;
#pragma unroll
    for (int j = 0; j < 4; j++) { o[j] = (short)f2bf(x0[j]); o[j + 4] = (short)f2bf(x1[j]); }
    *(bf16x8*)&d[i] = o;
}

// ---------------------------------------------------------------------------
// Pure-bf16 fused Q/K/V projection (m97 structure) + XCD-aware swizzle.
// Q pre-scaled by (1/8)*log2(e) for exp2-domain softmax.
// ---------------------------------------------------------------------------
__global__ __launch_bounds__(256, 3)
void qkv_gemm(const u16* __restrict__ qb, const u16* __restrict__ kb,
              const u16* __restrict__ vb, const u16* __restrict__ wb,
              u16* __restrict__ Qw, u16* __restrict__ Kw, u16* __restrict__ Vtw) {
    __shared__ u16 As[128][64];   // 16 KB, linear (global_load_lds dest)
    __shared__ u16 Bs[128][64];   // 16 KB

    const int hwid = blockIdx.x + 8 * blockIdx.y + 256 * blockIdx.z;
    const int lgc  = (hwid & 7) * 96 + (hwid >> 3);
    const int z    = lgc >> 8;
    const int m0   = ((lgc >> 3) & 31) * 128;
    const int n0   = (lgc & 7) * 128;

    const u16* A  = (z == 0) ? qb : (z == 1) ? kb : vb;
    const u16* Bm = wb + (size_t)z * 1048576;
    u16*      dst = (z == 0) ? Qw : (z == 1) ? Kw : Vtw;
    const float sc = (z == 0) ? 0.125f * 1.44269504088896f : 1.0f;

    const int t    = threadIdx.x;
    const int w    = t >> 6;
    const int ln   = t & 63;
    const int l16  = ln & 15;
    const int quad = ln >> 4;
    const int wr   = (w >> 1) * 64;
    const int wc   = (w & 1) * 64;
    const int sr   = ln >> 3;          // 0..7 row within chunk
    const int sc8  = (ln & 7) * 8;     // u16 col 0..56

    f32x4 acc[4][4];
#pragma unroll
    for (int i = 0; i < 4; i++)
#pragma unroll
        for (int j = 0; j < 4; j++) {
            f32x4 zz = {0.f, 0.f, 0.f, 0.f};
            acc[i][j] = zz;
        }

    for (int k0 = 0; k0 < 1024; k0 += 64) {
#pragma unroll
        for (int i = 0; i < 4; i++) {
            int chunk = w * 4 + i;                 // 0..15, rows chunk*8..+7
            int r = chunk * 8 + sr;
            gload16(&A [(size_t)(m0 + r) * 1024 + k0 + sc8], &As[chunk * 8][0]);
            gload16(&Bm[(size_t)(n0 + r) * 1024 + k0 + sc8], &Bs[chunk * 8][0]);
        }
        __syncthreads();
#pragma unroll
        for (int ks = 0; ks < 2; ks++) {
            bf16x8 af[4], bfr[4];
#pragma unroll
            for (int i = 0; i < 4; i++)
                af[i] = *(const bf16x8*)&As[wr + i * 16 + l16][ks * 32 + quad * 8];
#pragma unroll
            for (int j = 0; j < 4; j++)
                bfr[j] = *(const bf16x8*)&Bs[wc + j * 16 + l16][ks * 32 + quad * 8];
#pragma unroll
            for (int i = 0; i < 4; i++)
#pragma unroll
                for (int j = 0; j < 4; j++)
                    acc[i][j] = __builtin_amdgcn_mfma_f32_16x16x32_bf16(
                        af[i], bfr[j], acc[i][j], 0, 0, 0);
        }
        __syncthreads();
    }

#pragma unroll
    for (int i = 0; i < 4; i++)
#pragma unroll
        for (int j = 0; j < 4; j++)
#pragma unroll
            for (int r = 0; r < 4; r++) {
                int row = m0 + wr + i * 16 + quad * 4 + r;   // C: row=quad*4+reg
                int col = n0 + wc + j * 16 + l16;            //    col=lane&15
                float val = acc[i][j][r] * sc;
                int b = row >> 11, s = row & 2047, h = col >> 6, dk = col & 63;
                if (z < 2)
                    dst[((size_t)((b * 16 + h) * 2048 + s)) * 64 + dk] = f2bf(val);
                else
                    dst[((size_t)((b * 16 + h) * 64 + dk)) * 2048 + s] = f2bf(val);
            }
}

// ---------------------------------------------------------------------------
// Output projection: out = ctx_bf16 * wo^T + bias, fp32 out.
// BM=128 x BN=64 -> grid 512 blocks = 2 blocks/CU.
// ---------------------------------------------------------------------------
__global__ __launch_bounds__(256, 3)
void out_gemm(const u16* __restrict__ A, const u16* __restrict__ Bm,
              float* __restrict__ dst, const float* __restrict__ bias) {
    __shared__ u16 As[128][64];   // 16 KB
    __shared__ u16 Bs[64][64];    //  8 KB

    const int hwid = blockIdx.x + 16 * blockIdx.y;
    const int lgc  = (hwid & 7) * 64 + (hwid >> 3);
    const int m0   = (lgc >> 4) * 128;
    const int n0   = (lgc & 15) * 64;

    const int t    = threadIdx.x;
    const int w    = t >> 6;
    const int ln   = t & 63;
    const int l16  = ln & 15;
    const int quad = ln >> 4;
    const int wr   = (w >> 1) * 64;   // wave tile 64 x 32
    const int wc   = (w & 1) * 32;
    const int sr   = ln >> 3;
    const int sc8  = (ln & 7) * 8;

    f32x4 acc[4][2];
#pragma unroll
    for (int i = 0; i < 4; i++)
#pragma unroll
        for (int j = 0; j < 2; j++) {
            f32x4 zz = {0.f, 0.f, 0.f, 0.f};
            acc[i][j] = zz;
        }

    for (int k0 = 0; k0 < 1024; k0 += 64) {
#pragma unroll
        for (int i = 0; i < 4; i++) {
            int chunk = w * 4 + i;                 // A: 16 chunks
            int r = chunk * 8 + sr;
            gload16(&A[(size_t)(m0 + r) * 1024 + k0 + sc8], &As[chunk * 8][0]);
        }
#pragma unroll
        for (int i = 0; i < 2; i++) {
            int chunk = w * 2 + i;                 // B: 8 chunks
            int r = chunk * 8 + sr;
            gload16(&Bm[(size_t)(n0 + r) * 1024 + k0 + sc8], &Bs[chunk * 8][0]);
        }
        __syncthreads();
#pragma unroll
        for (int ks = 0; ks < 2; ks++) {
            bf16x8 af[4], bfr[2];
#pragma unroll
            for (int i = 0; i < 4; i++)
                af[i] = *(const bf16x8*)&As[wr + i * 16 + l16][ks * 32 + quad * 8];
#pragma unroll
            for (int j = 0; j < 2; j++)
                bfr[j] = *(const bf16x8*)&Bs[wc + j * 16 + l16][ks * 32 + quad * 8];
#pragma unroll
            for (int i = 0; i < 4; i++)
#pragma unroll
                for (int j = 0; j < 2; j++)
                    acc[i][j] = __builtin_amdgcn_mfma_f32_16x16x32_bf16(
                        af[i], bfr[j], acc[i][j], 0, 0, 0);
        }
        __syncthreads();
    }

#pragma unroll
    for (int i = 0; i < 4; i++)
#pragma unroll
        for (int j = 0; j < 2; j++)
#pragma unroll
            for (int r = 0; r < 4; r++) {
                int row = m0 + wr + i * 16 + quad * 4 + r;
                int col = n0 + wc + j * 16 + l16;
                dst[(size_t)row * 1024 + col] = acc[i][j][r] + bias[col];
            }
}

// ---------------------------------------------------------------------------
// Two-pass attention, QBLK=128, 512 threads (8 waves x 16 q-rows), m=0,
// log2-domain softmax. DE-STAGED: K and V fragments are read DIRECTLY from
// global (per-(b,h) K/V = 256 KB each, XCD-L2-resident; 16 KB tiles L1-hit
// across 16 waves/CU; each lane's fragment is a contiguous 16B dwordx4).
// LDS holds ONLY the wave-private Ps transpose -> ZERO barriers in the
// kernel; waves run free (latency hidden by 16 waves x 16 loads in flight).
// Mechanism: attn was LDS-pipe-bound (~80 DS ops/thread/kt in pass B);
// this cuts DS to 44 (pass B) / 0 (pass A) per m169's de-staging result.
// ---------------------------------------------------------------------------
__global__ __launch_bounds__(512, 4)
void attn_kernel(const u16* __restrict__ Qw, const u16* __restrict__ Kw,
                 const u16* __restrict__ Vtw,
                 float* __restrict__ attn_out, u16* __restrict__ ctx_out) {
    __shared__ u16 Ps[128][136];    // 34816 B, wave-private rows

    const int t    = threadIdx.x;
    const int hwid = blockIdx.x + 16 * blockIdx.y;
    const int lgc  = (hwid & 7) * 64 + (hwid >> 3);
    const int bh   = lgc >> 4;
    const int q0   = (lgc & 15) * 128;
    const int w    = t >> 6;
    const int lane = t & 63;
    const int l16  = lane & 15;
    const int quad = lane >> 4;

    const u16* Qh = Qw  + (size_t)bh * SEQ * DKD;
    const u16* Kh = Kw  + (size_t)bh * SEQ * DKD;
    const u16* Vh = Vtw + (size_t)bh * DKD * SEQ;

    // Q fragments in registers: wave w owns q-rows q0 + w*16 .. +15
    bf16x8 qf[2];
#pragma unroll
    for (int ks = 0; ks < 2; ks++)
        qf[ks] = *(const bf16x8*)&Qh[(size_t)(q0 + w * 16 + l16) * 64 + ks * 32 + quad * 8];

    // per-lane fragment base pointers (contiguous 16B per lane)
    const u16* Kb = Kh + (size_t)l16 * 64 + quad * 8;     // + (kt*128+j*16)*64 + ks*32
    const u16* Vb = Vh + (size_t)l16 * 2048 + quad * 8;   // + jo*16*2048 + kt*128 + ks*32

    float lsum[4];
#pragma unroll
    for (int r = 0; r < 4; r++) lsum[r] = 0.f;

    // ---------------- pass A: row denominators (m = 0), no LDS, no barriers -
    for (int kt = 0; kt < 16; kt++) {
        f32x4 s[8];
#pragma unroll
        for (int j = 0; j < 8; j++) { f32x4 zz = {0.f,0.f,0.f,0.f}; s[j] = zz; }
        __builtin_amdgcn_s_setprio(1);
#pragma unroll
        for (int ks = 0; ks < 2; ks++)
#pragma unroll
            for (int j = 0; j < 8; j++) {
                bf16x8 b = *(const bf16x8*)(Kb + (size_t)(kt * 128 + j * 16) * 64 + ks * 32);
                s[j] = __builtin_amdgcn_mfma_f32_16x16x32_bf16(qf[ks], b, s[j], 0, 0, 0);
            }
        __builtin_amdgcn_s_setprio(0);
#pragma unroll
        for (int j = 0; j < 8; j++)
#pragma unroll
            for (int r = 0; r < 4; r++)
                lsum[r] += exp2_hw(s[j][r]);
    }

    float lnl2[4];
#pragma unroll
    for (int r = 0; r < 4; r++) {
#pragma unroll
        for (int d = 1; d < 16; d <<= 1) lsum[r] += __shfl_xor(lsum[r], d, 64);
        lnl2[r] = log2_hw(lsum[r]);
    }

    f32x4 o[4];
#pragma unroll
    for (int jo = 0; jo < 4; jo++) { f32x4 zz = {0.f,0.f,0.f,0.f}; o[jo] = zz; }

    // ---------------- pass B: attn write + O accumulate, no barriers --------
    for (int kt = 0; kt < 16; kt++) {
        f32x4 s[8];
#pragma unroll
        for (int j = 0; j < 8; j++) { f32x4 zz = {0.f,0.f,0.f,0.f}; s[j] = zz; }
        __builtin_amdgcn_s_setprio(1);
#pragma unroll
        for (int ks = 0; ks < 2; ks++)
#pragma unroll
            for (int j = 0; j < 8; j++) {
                bf16x8 b = *(const bf16x8*)(Kb + (size_t)(kt * 128 + j * 16) * 64 + ks * 32);
                s[j] = __builtin_amdgcn_mfma_f32_16x16x32_bf16(qf[ks], b, s[j], 0, 0, 0);
            }
        __builtin_amdgcn_s_setprio(0);

        // p = exp2(s - log2 l) -> Ps (bf16, wave-private rows)
#pragma unroll
        for (int j = 0; j < 8; j++)
#pragma unroll
            for (int r = 0; r < 4; r++) {
                float p = exp2_hw(s[j][r] - lnl2[r]);
                Ps[w * 16 + quad * 4 + r][j * 16 + l16] = f2bf(p);
            }

        // O += P·V (pa from same-wave Ps rows; vb direct from global/L2)
        bf16x8 pa[4];
#pragma unroll
        for (int ks = 0; ks < 4; ks++)
            pa[ks] = *(const bf16x8*)&Ps[w * 16 + l16][ks * 32 + quad * 8];
        __builtin_amdgcn_s_setprio(1);
#pragma unroll
        for (int jo = 0; jo < 4; jo++)
#pragma unroll
            for (int ks = 0; ks < 4; ks++) {
                bf16x8 vb = *(const bf16x8*)(Vb + (size_t)jo * 32768 + kt * 128 + ks * 32);
                o[jo] = __builtin_amdgcn_mfma_f32_16x16x32_bf16(pa[ks], vb, o[jo], 0, 0, 0);
            }
        __builtin_amdgcn_s_setprio(0);

        // wave-local coalesced fp32 attn write: this wave's 16 rows x 128
        // cols, f32x4/lane NT (512B contiguous per 32-lane row segment)
#pragma unroll
        for (int i = 0; i < 8; i++) {
            int cw = lane + 64 * i;            // 0..511
            int r  = cw >> 5;                  // 0..15
            int c4 = (cw & 31) * 4;            // 0..124
            bf16x4 pv = *(const bf16x4*)&Ps[w * 16 + r][c4];
            f32x4 o4;
#pragma unroll
            for (int j = 0; j < 4; j++) o4[j] = bf2f((u16)pv[j]);
            __builtin_nontemporal_store(o4,
                (f32x4*)&attn_out[((size_t)(bh * 2048 + q0 + w * 16 + r)) * 2048 + kt * 128 + c4]);
        }
    }

    // write ctx [B,S,D] bf16
    const int b = bh >> 4, h = bh & 15;
#pragma unroll
    for (int jo = 0; jo < 4; jo++)
#pragma unroll
        for (int r = 0; r < 4; r++) {
            int srow = q0 + w * 16 + quad * 4 + r;
            int dcol = h * 64 + jo * 16 + l16;
            ctx_out[((size_t)(b * 2048 + srow)) * 1024 + dcol] = f2bf(o[jo][r]);
        }
}

// ---------------------------------------------------------------------------
extern "C" void kernel_launch(void* const* d_in, const int* in_sizes, int n_in,
                              void* d_out, int out_size, void* d_ws, size_t ws_size,
                              hipStream_t stream) {
    (void)in_sizes; (void)n_in; (void)out_size; (void)ws_size;

    const float* q  = (const float*)d_in[0];
    const float* k  = (const float*)d_in[1];
    const float* v  = (const float*)d_in[2];
    const float* wq = (const float*)d_in[3];
    const float* wk = (const float*)d_in[4];
    const float* wv = (const float*)d_in[5];
    const float* wo = (const float*)d_in[6];
    const float* bo = (const float*)d_in[7];

    float* out  = (float*)d_out;                   // [2,2048,1024] fp32
    float* attn = out + (size_t)4194304;           // [2,16,2048,2048] fp32

    // workspace layout (all 4M-element granules)
    u16* Qw   = (u16*)d_ws;                        // [B,H,S,64]  bf16  8 MB
    u16* Kw   = Qw   + (size_t)4194304;            // [B,H,S,64]  bf16  8 MB
    u16* Vtw  = Kw   + (size_t)4194304;            // [B,H,64,S]  bf16  8 MB
    u16* ctxb = Vtw  + (size_t)4194304;            // [B,S,D]     bf16  8 MB
    u16* qb   = ctxb + (size_t)4194304;            // bf16 inputs 8 MB
    u16* kb   = qb   + (size_t)4194304;            //             8 MB
    u16* vb   = kb   + (size_t)4194304;            //             8 MB
    u16* wb   = vb   + (size_t)4194304;            // wq|wk|wv|wo 8 MB

    dim3 blk(256);
    cast_all<<<dim3(512, 16), blk, 0, stream>>>(q, k, v, wq, wk, wv, wo,
                                                qb, kb, vb, wb);
    qkv_gemm<<<dim3(8, 32, 3), blk, 0, stream>>>(qb, kb, vb, wb, Qw, Kw, Vtw);
    attn_kernel<<<dim3(16, 32), dim3(512), 0, stream>>>(Qw, Kw, Vtw, attn, ctxb);
    out_gemm<<<dim3(16, 32), blk, 0, stream>>>(ctxb, wb + (size_t)3 * 1048576, out, bo);
}

// Round 9
// 844.418 us; speedup vs baseline: 1.0883x; 1.0883x over previous
//
#include <hip/hip_runtime.h>
#include <cstdint>
#include <cstddef>

#define SEQ   2048
#define NH    16
#define DKD   64
#define DM    1024

typedef __attribute__((ext_vector_type(8))) short bf16x8;
typedef __attribute__((ext_vector_type(4))) short bf16x4;
typedef __attribute__((ext_vector_type(4))) float f32x4;
typedef unsigned short u16;

__device__ __forceinline__ u16 f2bf(float f) {
    union { float f; unsigned u; } v; v.f = f;
    unsigned r = v.u + 0x7fff + ((v.u >> 16) & 1);   // RNE
    return (u16)(r >> 16);
}
__device__ __forceinline__ float bf2f(u16 b) {
    union { unsigned u; float f; } v; v.u = ((unsigned)b) << 16;
    return v.f;
}
// raw ISA transcendentals (glibc macro collision avoids __exp2f/__log2f):
__device__ __forceinline__ float exp2_hw(float x) { return __builtin_amdgcn_exp2f(x); }
__device__ __forceinline__ float log2_hw(float x) { return __builtin_amdgcn_logf(x); }

// async global->LDS, 16B per lane. LDS dest = wave-uniform base + lane*16.
__device__ __forceinline__ void gload16(const void* g, void* l) {
    __builtin_amdgcn_global_load_lds(
        (const __attribute__((address_space(1))) void*)g,
        (__attribute__((address_space(3))) void*)l, 16, 0, 0);
}

// ---------------------------------------------------------------------------
// One-shot fp32 -> bf16 cast of q,k,v and wq,wk,wv,wo (into wb). RNE.
// ---------------------------------------------------------------------------
__global__ __launch_bounds__(256)
void cast_all(const float* __restrict__ q, const float* __restrict__ k,
              const float* __restrict__ v, const float* __restrict__ wq,
              const float* __restrict__ wk, const float* __restrict__ wv,
              const float* __restrict__ wo,
              u16* __restrict__ qb, u16* __restrict__ kb, u16* __restrict__ vb,
              u16* __restrict__ wb) {
    const int z = blockIdx.y;
    const float* s;
    u16* d;
    if (z < 12) {
        int a = z >> 2;
        s = (a == 0 ? q : a == 1 ? k : v) + (size_t)(z & 3) * 1048576;
        d = (a == 0 ? qb : a == 1 ? kb : vb) + (size_t)(z & 3) * 1048576;
    } else {
        int a = z - 12;
        s = (a == 0 ? wq : a == 1 ? wk : a == 2 ? wv : wo);
        d = wb + (size_t)a * 1048576;
    }
    size_t i = ((size_t)blockIdx.x * 256 + threadIdx.x) * 8;
    f32x4 x0 = *(const f32x4*)&s[i];
    f32x4 x1 = *(const f32x4*)&s[i + 4];
    bf16x8 o;
#pragma unroll
    for (int j = 0; j < 4; j++) { o[j] = (short)f2bf(x0[j]); o[j + 4] = (short)f2bf(x1[j]); }
    *(bf16x8*)&d[i] = o;
}

// ---------------------------------------------------------------------------
// Pure-bf16 fused Q/K/V projection (m97 structure) + XCD-aware swizzle.
// Q pre-scaled by (1/8)*log2(e) for exp2-domain softmax.
// ---------------------------------------------------------------------------
__global__ __launch_bounds__(256, 3)
void qkv_gemm(const u16* __restrict__ qb, const u16* __restrict__ kb,
              const u16* __restrict__ vb, const u16* __restrict__ wb,
              u16* __restrict__ Qw, u16* __restrict__ Kw, u16* __restrict__ Vtw) {
    __shared__ u16 As[128][64];   // 16 KB, linear (global_load_lds dest)
    __shared__ u16 Bs[128][64];   // 16 KB

    const int hwid = blockIdx.x + 8 * blockIdx.y + 256 * blockIdx.z;
    const int lgc  = (hwid & 7) * 96 + (hwid >> 3);
    const int z    = lgc >> 8;
    const int m0   = ((lgc >> 3) & 31) * 128;
    const int n0   = (lgc & 7) * 128;

    const u16* A  = (z == 0) ? qb : (z == 1) ? kb : vb;
    const u16* Bm = wb + (size_t)z * 1048576;
    u16*      dst = (z == 0) ? Qw : (z == 1) ? Kw : Vtw;
    const float sc = (z == 0) ? 0.125f * 1.44269504088896f : 1.0f;

    const int t    = threadIdx.x;
    const int w    = t >> 6;
    const int ln   = t & 63;
    const int l16  = ln & 15;
    const int quad = ln >> 4;
    const int wr   = (w >> 1) * 64;
    const int wc   = (w & 1) * 64;
    const int sr   = ln >> 3;          // 0..7 row within chunk
    const int sc8  = (ln & 7) * 8;     // u16 col 0..56

    f32x4 acc[4][4];
#pragma unroll
    for (int i = 0; i < 4; i++)
#pragma unroll
        for (int j = 0; j < 4; j++) {
            f32x4 zz = {0.f, 0.f, 0.f, 0.f};
            acc[i][j] = zz;
        }

    for (int k0 = 0; k0 < 1024; k0 += 64) {
#pragma unroll
        for (int i = 0; i < 4; i++) {
            int chunk = w * 4 + i;                 // 0..15, rows chunk*8..+7
            int r = chunk * 8 + sr;
            gload16(&A [(size_t)(m0 + r) * 1024 + k0 + sc8], &As[chunk * 8][0]);
            gload16(&Bm[(size_t)(n0 + r) * 1024 + k0 + sc8], &Bs[chunk * 8][0]);
        }
        __syncthreads();
#pragma unroll
        for (int ks = 0; ks < 2; ks++) {
            bf16x8 af[4], bfr[4];
#pragma unroll
            for (int i = 0; i < 4; i++)
                af[i] = *(const bf16x8*)&As[wr + i * 16 + l16][ks * 32 + quad * 8];
#pragma unroll
            for (int j = 0; j < 4; j++)
                bfr[j] = *(const bf16x8*)&Bs[wc + j * 16 + l16][ks * 32 + quad * 8];
#pragma unroll
            for (int i = 0; i < 4; i++)
#pragma unroll
                for (int j = 0; j < 4; j++)
                    acc[i][j] = __builtin_amdgcn_mfma_f32_16x16x32_bf16(
                        af[i], bfr[j], acc[i][j], 0, 0, 0);
        }
        __syncthreads();
    }

#pragma unroll
    for (int i = 0; i < 4; i++)
#pragma unroll
        for (int j = 0; j < 4; j++)
#pragma unroll
            for (int r = 0; r < 4; r++) {
                int row = m0 + wr + i * 16 + quad * 4 + r;   // C: row=quad*4+reg
                int col = n0 + wc + j * 16 + l16;            //    col=lane&15
                float val = acc[i][j][r] * sc;
                int b = row >> 11, s = row & 2047, h = col >> 6, dk = col & 63;
                if (z < 2)
                    dst[((size_t)((b * 16 + h) * 2048 + s)) * 64 + dk] = f2bf(val);
                else
                    dst[((size_t)((b * 16 + h) * 64 + dk)) * 2048 + s] = f2bf(val);
            }
}

// ---------------------------------------------------------------------------
// Output projection: out = ctx_bf16 * wo^T + bias, fp32 out.
// BM=128 x BN=64 -> grid 512 blocks = 2 blocks/CU.
// ---------------------------------------------------------------------------
__global__ __launch_bounds__(256, 3)
void out_gemm(const u16* __restrict__ A, const u16* __restrict__ Bm,
              float* __restrict__ dst, const float* __restrict__ bias) {
    __shared__ u16 As[128][64];   // 16 KB
    __shared__ u16 Bs[64][64];    //  8 KB

    const int hwid = blockIdx.x + 16 * blockIdx.y;
    const int lgc  = (hwid & 7) * 64 + (hwid >> 3);
    const int m0   = (lgc >> 4) * 128;
    const int n0   = (lgc & 15) * 64;

    const int t    = threadIdx.x;
    const int w    = t >> 6;
    const int ln   = t & 63;
    const int l16  = ln & 15;
    const int quad = ln >> 4;
    const int wr   = (w >> 1) * 64;   // wave tile 64 x 32
    const int wc   = (w & 1) * 32;
    const int sr   = ln >> 3;
    const int sc8  = (ln & 7) * 8;

    f32x4 acc[4][2];
#pragma unroll
    for (int i = 0; i < 4; i++)
#pragma unroll
        for (int j = 0; j < 2; j++) {
            f32x4 zz = {0.f, 0.f, 0.f, 0.f};
            acc[i][j] = zz;
        }

    for (int k0 = 0; k0 < 1024; k0 += 64) {
#pragma unroll
        for (int i = 0; i < 4; i++) {
            int chunk = w * 4 + i;                 // A: 16 chunks
            int r = chunk * 8 + sr;
            gload16(&A[(size_t)(m0 + r) * 1024 + k0 + sc8], &As[chunk * 8][0]);
        }
#pragma unroll
        for (int i = 0; i < 2; i++) {
            int chunk = w * 2 + i;                 // B: 8 chunks
            int r = chunk * 8 + sr;
            gload16(&Bm[(size_t)(n0 + r) * 1024 + k0 + sc8], &Bs[chunk * 8][0]);
        }
        __syncthreads();
#pragma unroll
        for (int ks = 0; ks < 2; ks++) {
            bf16x8 af[4], bfr[2];
#pragma unroll
            for (int i = 0; i < 4; i++)
                af[i] = *(const bf16x8*)&As[wr + i * 16 + l16][ks * 32 + quad * 8];
#pragma unroll
            for (int j = 0; j < 2; j++)
                bfr[j] = *(const bf16x8*)&Bs[wc + j * 16 + l16][ks * 32 + quad * 8];
#pragma unroll
            for (int i = 0; i < 4; i++)
#pragma unroll
                for (int j = 0; j < 2; j++)
                    acc[i][j] = __builtin_amdgcn_mfma_f32_16x16x32_bf16(
                        af[i], bfr[j], acc[i][j], 0, 0, 0);
        }
        __syncthreads();
    }

#pragma unroll
    for (int i = 0; i < 4; i++)
#pragma unroll
        for (int j = 0; j < 2; j++)
#pragma unroll
            for (int r = 0; r < 4; r++) {
                int row = m0 + wr + i * 16 + quad * 4 + r;
                int col = n0 + wc + j * 16 + l16;
                dst[(size_t)row * 1024 + col] = acc[i][j][r] + bias[col];
            }
}

// ---------------------------------------------------------------------------
// Two-pass attention, QBLK=128, 512 threads (8 waves x 16 q-rows), m=0,
// log2-domain softmax. Hybrid staging per R8's counters:
//  - K: LDS-staged + reg-prefetch + double-buffer (QK consumes immediately;
//    R8's direct-K exposed ~200cy L2 latency, MfmaUtil 5.5%).
//  - V: DIRECT from global to registers (FETCH=12MB proved L2-residency).
//    Issued in two 8-load batches (before barrier / after QK) and consumed
//    ~400cy later in PV -> latency fully hidden, VGPR peak kept < 128.
// Pass A: 1 barrier/kt. Pass B: now also 1 barrier/kt (V no longer in LDS,
// K double-buffers in H[2]). Ps (wave-private) is the only other LDS use.
// ---------------------------------------------------------------------------
__global__ __launch_bounds__(512, 4)
void attn_kernel(const u16* __restrict__ Qw, const u16* __restrict__ Kw,
                 const u16* __restrict__ Vtw,
                 float* __restrict__ attn_out, u16* __restrict__ ctx_out) {
    __shared__ u16 H[2][128][72];   // 36864 B: K double-buffer (both passes)
    __shared__ u16 Ps[128][136];    // 34816 B (wave-private rows in pass B)

    const int t    = threadIdx.x;
    const int hwid = blockIdx.x + 16 * blockIdx.y;
    const int lgc  = (hwid & 7) * 64 + (hwid >> 3);
    const int bh   = lgc >> 4;
    const int q0   = (lgc & 15) * 128;
    const int w    = t >> 6;
    const int lane = t & 63;
    const int l16  = lane & 15;
    const int quad = lane >> 4;

    const u16* Qh = Qw  + (size_t)bh * SEQ * DKD;
    const u16* Kh = Kw  + (size_t)bh * SEQ * DKD;
    const u16* Vh = Vtw + (size_t)bh * DKD * SEQ;

    // Q fragments in registers: wave w owns q-rows q0 + w*16 .. +15
    bf16x8 qf[2];
#pragma unroll
    for (int ks = 0; ks < 2; ks++)
        qf[ks] = *(const bf16x8*)&Qh[(size_t)(q0 + w * 16 + l16) * 64 + ks * 32 + quad * 8];

    // K staging indices (128x64 tile, 2 chunks/thread)
    const int kr0 = t >> 3,         kc0 = (t & 7) * 8;
    const int kr1 = (t + 512) >> 3, kc1 = ((t + 512) & 7) * 8;
    // per-lane V fragment base (contiguous 16B per lane, direct global)
    const u16* Vb = Vh + (size_t)l16 * 2048 + quad * 8;   // + jo*16*2048 + kt*128 + ks*32

    float lsum[4];
#pragma unroll
    for (int r = 0; r < 4; r++) lsum[r] = 0.f;

    // ---------------- pass A: row denominators (m = 0), 1 barrier/kt --------
    bf16x8 kp0 = *(const bf16x8*)&Kh[(size_t)kr0 * 64 + kc0];
    bf16x8 kp1 = *(const bf16x8*)&Kh[(size_t)kr1 * 64 + kc1];
    for (int kt = 0; kt < 16; kt++) {
        u16 (*KA)[72] = H[kt & 1];
        *(bf16x8*)&KA[kr0][kc0] = kp0;
        *(bf16x8*)&KA[kr1][kc1] = kp1;
        if (kt < 15) {
            kp0 = *(const bf16x8*)&Kh[(size_t)((kt + 1) * 128 + kr0) * 64 + kc0];
            kp1 = *(const bf16x8*)&Kh[(size_t)((kt + 1) * 128 + kr1) * 64 + kc1];
        }
        __syncthreads();

        f32x4 s[8];
#pragma unroll
        for (int j = 0; j < 8; j++) { f32x4 zz = {0.f,0.f,0.f,0.f}; s[j] = zz; }
        __builtin_amdgcn_s_setprio(1);
#pragma unroll
        for (int ks = 0; ks < 2; ks++)
#pragma unroll
            for (int j = 0; j < 8; j++) {
                bf16x8 b = *(const bf16x8*)&KA[j * 16 + l16][ks * 32 + quad * 8];
                s[j] = __builtin_amdgcn_mfma_f32_16x16x32_bf16(qf[ks], b, s[j], 0, 0, 0);
            }
        __builtin_amdgcn_s_setprio(0);
#pragma unroll
        for (int j = 0; j < 8; j++)
#pragma unroll
            for (int r = 0; r < 4; r++)
                lsum[r] += exp2_hw(s[j][r]);
    }

    float lnl2[4];
#pragma unroll
    for (int r = 0; r < 4; r++) {
#pragma unroll
        for (int d = 1; d < 16; d <<= 1) lsum[r] += __shfl_xor(lsum[r], d, 64);
        lnl2[r] = log2_hw(lsum[r]);
    }

    f32x4 o[4];
#pragma unroll
    for (int jo = 0; jo < 4; jo++) { f32x4 zz = {0.f,0.f,0.f,0.f}; o[jo] = zz; }

    // ---------------- pass B: attn write + O accumulate, 1 barrier/kt -------
    kp0 = *(const bf16x8*)&Kh[(size_t)kr0 * 64 + kc0];
    kp1 = *(const bf16x8*)&Kh[(size_t)kr1 * 64 + kc1];
    for (int kt = 0; kt < 16; kt++) {
        u16 (*KA)[72] = H[kt & 1];
        *(bf16x8*)&KA[kr0][kc0] = kp0;
        *(bf16x8*)&KA[kr1][kc1] = kp1;
        // V batch 0 (jo=0,1): issue now, consumed after QK+softmax (~400cy)
        bf16x8 vf0[2][4];
#pragma unroll
        for (int jo = 0; jo < 2; jo++)
#pragma unroll
            for (int ks = 0; ks < 4; ks++)
                vf0[jo][ks] = *(const bf16x8*)(Vb + (size_t)jo * 32768 + kt * 128 + ks * 32);
        if (kt < 15) {
            kp0 = *(const bf16x8*)&Kh[(size_t)((kt + 1) * 128 + kr0) * 64 + kc0];
            kp1 = *(const bf16x8*)&Kh[(size_t)((kt + 1) * 128 + kr1) * 64 + kc1];
        }
        __syncthreads();                 // K staged (dbuf: other buffer safe)

        f32x4 s[8];
#pragma unroll
        for (int j = 0; j < 8; j++) { f32x4 zz = {0.f,0.f,0.f,0.f}; s[j] = zz; }
        __builtin_amdgcn_s_setprio(1);
#pragma unroll
        for (int ks = 0; ks < 2; ks++)
#pragma unroll
            for (int j = 0; j < 8; j++) {
                bf16x8 b = *(const bf16x8*)&KA[j * 16 + l16][ks * 32 + quad * 8];
                s[j] = __builtin_amdgcn_mfma_f32_16x16x32_bf16(qf[ks], b, s[j], 0, 0, 0);
            }
        __builtin_amdgcn_s_setprio(0);

        // V batch 1 (jo=2,3): issue now, consumed after softmax + 8 PV MFMAs
        bf16x8 vf1[2][4];
#pragma unroll
        for (int jo = 0; jo < 2; jo++)
#pragma unroll
            for (int ks = 0; ks < 4; ks++)
                vf1[jo][ks] = *(const bf16x8*)(Vb + (size_t)(jo + 2) * 32768 + kt * 128 + ks * 32);

        // p = exp2(s - log2 l) -> Ps (bf16, wave-private rows)
#pragma unroll
        for (int j = 0; j < 8; j++)
#pragma unroll
            for (int r = 0; r < 4; r++) {
                float p = exp2_hw(s[j][r] - lnl2[r]);
                Ps[w * 16 + quad * 4 + r][j * 16 + l16] = f2bf(p);
            }

        // O += P·V (pa from same-wave Ps rows; V from registers)
        bf16x8 pa[4];
#pragma unroll
        for (int ks = 0; ks < 4; ks++)
            pa[ks] = *(const bf16x8*)&Ps[w * 16 + l16][ks * 32 + quad * 8];
        __builtin_amdgcn_s_setprio(1);
#pragma unroll
        for (int jo = 0; jo < 2; jo++)
#pragma unroll
            for (int ks = 0; ks < 4; ks++)
                o[jo] = __builtin_amdgcn_mfma_f32_16x16x32_bf16(pa[ks], vf0[jo][ks], o[jo], 0, 0, 0);
#pragma unroll
        for (int jo = 0; jo < 2; jo++)
#pragma unroll
            for (int ks = 0; ks < 4; ks++)
                o[jo + 2] = __builtin_amdgcn_mfma_f32_16x16x32_bf16(pa[ks], vf1[jo][ks], o[jo + 2], 0, 0, 0);
        __builtin_amdgcn_s_setprio(0);

        // wave-local coalesced fp32 attn write: this wave's 16 rows x 128
        // cols, f32x4/lane NT (512B contiguous per 32-lane row segment)
#pragma unroll
        for (int i = 0; i < 8; i++) {
            int cw = lane + 64 * i;            // 0..511
            int r  = cw >> 5;                  // 0..15
            int c4 = (cw & 31) * 4;            // 0..124
            bf16x4 pv = *(const bf16x4*)&Ps[w * 16 + r][c4];
            f32x4 o4;
#pragma unroll
            for (int j = 0; j < 4; j++) o4[j] = bf2f((u16)pv[j]);
            __builtin_nontemporal_store(o4,
                (f32x4*)&attn_out[((size_t)(bh * 2048 + q0 + w * 16 + r)) * 2048 + kt * 128 + c4]);
        }
    }

    // write ctx [B,S,D] bf16
    const int b = bh >> 4, h = bh & 15;
#pragma unroll
    for (int jo = 0; jo < 4; jo++)
#pragma unroll
        for (int r = 0; r < 4; r++) {
            int srow = q0 + w * 16 + quad * 4 + r;
            int dcol = h * 64 + jo * 16 + l16;
            ctx_out[((size_t)(b * 2048 + srow)) * 1024 + dcol] = f2bf(o[jo][r]);
        }
}

// ---------------------------------------------------------------------------
extern "C" void kernel_launch(void* const* d_in, const int* in_sizes, int n_in,
                              void* d_out, int out_size, void* d_ws, size_t ws_size,
                              hipStream_t stream) {
    (void)in_sizes; (void)n_in; (void)out_size; (void)ws_size;

    const float* q  = (const float*)d_in[0];
    const float* k  = (const float*)d_in[1];
    const float* v  = (const float*)d_in[2];
    const float* wq = (const float*)d_in[3];
    const float* wk = (const float*)d_in[4];
    const float* wv = (const float*)d_in[5];
    const float* wo = (const float*)d_in[6];
    const float* bo = (const float*)d_in[7];

    float* out  = (float*)d_out;                   // [2,2048,1024] fp32
    float* attn = out + (size_t)4194304;           // [2,16,2048,2048] fp32

    // workspace layout (all 4M-element granules)
    u16* Qw   = (u16*)d_ws;                        // [B,H,S,64]  bf16  8 MB
    u16* Kw   = Qw   + (size_t)4194304;            // [B,H,S,64]  bf16  8 MB
    u16* Vtw  = Kw   + (size_t)4194304;            // [B,H,64,S]  bf16  8 MB
    u16* ctxb = Vtw  + (size_t)4194304;            // [B,S,D]     bf16  8 MB
    u16* qb   = ctxb + (size_t)4194304;            // bf16 inputs 8 MB
    u16* kb   = qb   + (size_t)4194304;            //             8 MB
    u16* vb   = kb   + (size_t)4194304;            //             8 MB
    u16* wb   = vb   + (size_t)4194304;            // wq|wk|wv|wo 8 MB

    dim3 blk(256);
    cast_all<<<dim3(512, 16), blk, 0, stream>>>(q, k, v, wq, wk, wv, wo,
                                                qb, kb, vb, wb);
    qkv_gemm<<<dim3(8, 32, 3), blk, 0, stream>>>(qb, kb, vb, wb, Qw, Kw, Vtw);
    attn_kernel<<<dim3(16, 32), dim3(512), 0, stream>>>(Qw, Kw, Vtw, attn, ctxb);
    out_gemm<<<dim3(16, 32), blk, 0, stream>>>(ctxb, wb + (size_t)3 * 1048576, out, bo);
}

// Round 10
// 679.110 us; speedup vs baseline: 1.3532x; 1.2434x over previous
//
#include <hip/hip_runtime.h>
#include <cstdint>
#include <cstddef>

#define SEQ   2048
#define NH    16
#define DKD   64
#define DM    1024

typedef __attribute__((ext_vector_type(8))) short bf16x8;
typedef __attribute__((ext_vector_type(4))) short bf16x4;
typedef __attribute__((ext_vector_type(4))) float f32x4;
typedef unsigned short u16;

__device__ __forceinline__ u16 f2bf(float f) {
    union { float f; unsigned u; } v; v.f = f;
    unsigned r = v.u + 0x7fff + ((v.u >> 16) & 1);   // RNE
    return (u16)(r >> 16);
}
__device__ __forceinline__ float bf2f(u16 b) {
    union { unsigned u; float f; } v; v.u = ((unsigned)b) << 16;
    return v.f;
}
// raw ISA transcendentals (glibc macro collision avoids __exp2f/__log2f):
__device__ __forceinline__ float exp2_hw(float x) { return __builtin_amdgcn_exp2f(x); }
__device__ __forceinline__ float log2_hw(float x) { return __builtin_amdgcn_logf(x); }

// async global->LDS, 16B per lane. LDS dest = wave-uniform base + lane*16.
__device__ __forceinline__ void gload16(const void* g, void* l) {
    __builtin_amdgcn_global_load_lds(
        (const __attribute__((address_space(1))) void*)g,
        (__attribute__((address_space(3))) void*)l, 16, 0, 0);
}

// ---------------------------------------------------------------------------
// One-shot fp32 -> bf16 cast of q,k,v and wq,wk,wv,wo (into wb). RNE.
// ---------------------------------------------------------------------------
__global__ __launch_bounds__(256)
void cast_all(const float* __restrict__ q, const float* __restrict__ k,
              const float* __restrict__ v, const float* __restrict__ wq,
              const float* __restrict__ wk, const float* __restrict__ wv,
              const float* __restrict__ wo,
              u16* __restrict__ qb, u16* __restrict__ kb, u16* __restrict__ vb,
              u16* __restrict__ wb) {
    const int z = blockIdx.y;
    const float* s;
    u16* d;
    if (z < 12) {
        int a = z >> 2;
        s = (a == 0 ? q : a == 1 ? k : v) + (size_t)(z & 3) * 1048576;
        d = (a == 0 ? qb : a == 1 ? kb : vb) + (size_t)(z & 3) * 1048576;
    } else {
        int a = z - 12;
        s = (a == 0 ? wq : a == 1 ? wk : a == 2 ? wv : wo);
        d = wb + (size_t)a * 1048576;
    }
    size_t i = ((size_t)blockIdx.x * 256 + threadIdx.x) * 8;
    f32x4 x0 = *(const f32x4*)&s[i];
    f32x4 x1 = *(const f32x4*)&s[i + 4];
    bf16x8 o;
#pragma unroll
    for (int j = 0; j < 4; j++) { o[j] = (short)f2bf(x0[j]); o[j + 4] = (short)f2bf(x1[j]); }
    *(bf16x8*)&d[i] = o;
}

// ---------------------------------------------------------------------------
// Pure-bf16 fused Q/K/V projection (m97 structure) + XCD-aware swizzle.
// Q pre-scaled by (1/8)*log2(e) for exp2-domain softmax.
// NEW: epilogue stages the C-tile through LDS (reusing As/Bs, XOR-swizzled)
// so all three output modes store fully-coalesced bf16x8 (16B/lane) instead
// of 16x 2B scatters/thread (32B segments, ~2x write amplification).
// ---------------------------------------------------------------------------
__global__ __launch_bounds__(256, 3)
void qkv_gemm(const u16* __restrict__ qb, const u16* __restrict__ kb,
              const u16* __restrict__ vb, const u16* __restrict__ wb,
              u16* __restrict__ Qw, u16* __restrict__ Kw, u16* __restrict__ Vtw) {
    __shared__ u16 S[16384];      // 32 KB: As(16K) + Bs(16K) in loop; Ct in epilogue
    u16 (*As)[64]  = (u16(*)[64])S;
    u16 (*Bs)[64]  = (u16(*)[64])(S + 8192);
    u16 (*Ct)[128] = (u16(*)[128])S;

    const int hwid = blockIdx.x + 8 * blockIdx.y + 256 * blockIdx.z;
    const int lgc  = (hwid & 7) * 96 + (hwid >> 3);
    const int z    = lgc >> 8;
    const int m0   = ((lgc >> 3) & 31) * 128;
    const int n0   = (lgc & 7) * 128;

    const u16* A  = (z == 0) ? qb : (z == 1) ? kb : vb;
    const u16* Bm = wb + (size_t)z * 1048576;
    u16*      dst = (z == 0) ? Qw : (z == 1) ? Kw : Vtw;
    const float sc = (z == 0) ? 0.125f * 1.44269504088896f : 1.0f;

    const int t    = threadIdx.x;
    const int w    = t >> 6;
    const int ln   = t & 63;
    const int l16  = ln & 15;
    const int quad = ln >> 4;
    const int wr   = (w >> 1) * 64;
    const int wc   = (w & 1) * 64;

    f32x4 acc[4][4];
#pragma unroll
    for (int i = 0; i < 4; i++)
#pragma unroll
        for (int j = 0; j < 4; j++) {
            f32x4 zz = {0.f, 0.f, 0.f, 0.f};
            acc[i][j] = zz;
        }

    for (int k0 = 0; k0 < 1024; k0 += 64) {
#pragma unroll
        for (int i = 0; i < 4; i++) {
            int chunk = w * 4 + i;                 // 0..15, rows chunk*8..+7
            int r = chunk * 8 + (ln >> 3);
            int c8 = (ln & 7) * 8;
            gload16(&A [(size_t)(m0 + r) * 1024 + k0 + c8], &As[chunk * 8][0]);
            gload16(&Bm[(size_t)(n0 + r) * 1024 + k0 + c8], &Bs[chunk * 8][0]);
        }
        __syncthreads();
#pragma unroll
        for (int ks = 0; ks < 2; ks++) {
            bf16x8 af[4], bfr[4];
#pragma unroll
            for (int i = 0; i < 4; i++)
                af[i] = *(const bf16x8*)&As[wr + i * 16 + l16][ks * 32 + quad * 8];
#pragma unroll
            for (int j = 0; j < 4; j++)
                bfr[j] = *(const bf16x8*)&Bs[wc + j * 16 + l16][ks * 32 + quad * 8];
#pragma unroll
            for (int i = 0; i < 4; i++)
#pragma unroll
                for (int j = 0; j < 4; j++)
                    acc[i][j] = __builtin_amdgcn_mfma_f32_16x16x32_bf16(
                        af[i], bfr[j], acc[i][j], 0, 0, 0);
        }
        __syncthreads();                 // also frees As/Bs for the epilogue
    }

    // ---- epilogue: C -> LDS (XOR-swizzled scatter) -> coalesced stores ----
    if (z < 2) {
        // Ct[row=s-local][col=(h,dk)-local]
#pragma unroll
        for (int i = 0; i < 4; i++)
#pragma unroll
            for (int j = 0; j < 4; j++)
#pragma unroll
                for (int r = 0; r < 4; r++) {
                    int row = wr + i * 16 + quad * 4 + r;
                    int col = wc + j * 16 + l16;
                    Ct[row][col ^ ((row & 7) << 4)] = f2bf(acc[i][j][r] * sc);
                }
        __syncthreads();
#pragma unroll
        for (int it = 0; it < 8; it++) {
            int c    = t + 256 * it;           // 0..2047
            int row  = c >> 4;                 // 0..127
            int col8 = (c & 15) * 8;           // 8-aligned, within one 64-block
            bf16x8 vv = *(const bf16x8*)&Ct[row][col8 ^ ((row & 7) << 4)];
            int grow = m0 + row, gcol = n0 + col8;
            int b = grow >> 11, s = grow & 2047, h = gcol >> 6, dk = gcol & 63;
            *(bf16x8*)&dst[((size_t)((b * 16 + h) * 2048 + s)) * 64 + dk] = vv;
        }
    } else {
        // transposed stage: Ct[row=(h,dk)-local][col=s-local]
#pragma unroll
        for (int i = 0; i < 4; i++)
#pragma unroll
            for (int j = 0; j < 4; j++)
#pragma unroll
                for (int r = 0; r < 4; r++) {
                    int rowL = wc + j * 16 + l16;           // (h,dk)
                    int colL = wr + i * 16 + quad * 4 + r;  // s
                    Ct[rowL][colL ^ ((rowL & 7) << 4)] = f2bf(acc[i][j][r]);
                }
        __syncthreads();
#pragma unroll
        for (int it = 0; it < 8; it++) {
            int c    = t + 256 * it;
            int rowL = c >> 4;                 // (h,dk) 0..127
            int s8   = (c & 15) * 8;           // s-local, 8-aligned
            bf16x8 vv = *(const bf16x8*)&Ct[rowL][s8 ^ ((rowL & 7) << 4)];
            int gcol = n0 + rowL;
            int h = gcol >> 6, dk = gcol & 63;
            int grow = m0 + s8;
            int b = grow >> 11, s = grow & 2047;
            *(bf16x8*)&dst[((size_t)((b * 16 + h) * 64 + dk)) * 2048 + s] = vv;
        }
    }
}

// ---------------------------------------------------------------------------
// Output projection: out = ctx_bf16 * wo^T + bias, fp32 out.
// BM=128 x BN=64 -> grid 512 blocks = 2 blocks/CU.
// ---------------------------------------------------------------------------
__global__ __launch_bounds__(256, 3)
void out_gemm(const u16* __restrict__ A, const u16* __restrict__ Bm,
              float* __restrict__ dst, const float* __restrict__ bias) {
    __shared__ u16 As[128][64];   // 16 KB
    __shared__ u16 Bs[64][64];    //  8 KB

    const int hwid = blockIdx.x + 16 * blockIdx.y;
    const int lgc  = (hwid & 7) * 64 + (hwid >> 3);
    const int m0   = (lgc >> 4) * 128;
    const int n0   = (lgc & 15) * 64;

    const int t    = threadIdx.x;
    const int w    = t >> 6;
    const int ln   = t & 63;
    const int l16  = ln & 15;
    const int quad = ln >> 4;
    const int wr   = (w >> 1) * 64;   // wave tile 64 x 32
    const int wc   = (w & 1) * 32;
    const int sr   = ln >> 3;
    const int sc8  = (ln & 7) * 8;

    f32x4 acc[4][2];
#pragma unroll
    for (int i = 0; i < 4; i++)
#pragma unroll
        for (int j = 0; j < 2; j++) {
            f32x4 zz = {0.f, 0.f, 0.f, 0.f};
            acc[i][j] = zz;
        }

    for (int k0 = 0; k0 < 1024; k0 += 64) {
#pragma unroll
        for (int i = 0; i < 4; i++) {
            int chunk = w * 4 + i;                 // A: 16 chunks
            int r = chunk * 8 + sr;
            gload16(&A[(size_t)(m0 + r) * 1024 + k0 + sc8], &As[chunk * 8][0]);
        }
#pragma unroll
        for (int i = 0; i < 2; i++) {
            int chunk = w * 2 + i;                 // B: 8 chunks
            int r = chunk * 8 + sr;
            gload16(&Bm[(size_t)(n0 + r) * 1024 + k0 + sc8], &Bs[chunk * 8][0]);
        }
        __syncthreads();
#pragma unroll
        for (int ks = 0; ks < 2; ks++) {
            bf16x8 af[4], bfr[2];
#pragma unroll
            for (int i = 0; i < 4; i++)
                af[i] = *(const bf16x8*)&As[wr + i * 16 + l16][ks * 32 + quad * 8];
#pragma unroll
            for (int j = 0; j < 2; j++)
                bfr[j] = *(const bf16x8*)&Bs[wc + j * 16 + l16][ks * 32 + quad * 8];
#pragma unroll
            for (int i = 0; i < 4; i++)
#pragma unroll
                for (int j = 0; j < 2; j++)
                    acc[i][j] = __builtin_amdgcn_mfma_f32_16x16x32_bf16(
                        af[i], bfr[j], acc[i][j], 0, 0, 0);
        }
        __syncthreads();
    }

#pragma unroll
    for (int i = 0; i < 4; i++)
#pragma unroll
        for (int j = 0; j < 2; j++)
#pragma unroll
            for (int r = 0; r < 4; r++) {
                int row = m0 + wr + i * 16 + quad * 4 + r;
                int col = n0 + wc + j * 16 + l16;
                dst[(size_t)row * 1024 + col] = acc[i][j][r] + bias[col];
            }
}

// ---------------------------------------------------------------------------
// Two-pass attention — EXACT R7 structure (best measured: 699/698 µs total).
// QBLK=128, 512 threads, m=0, log2-domain softmax. K LDS-staged with
// reg-prefetch (R8 proved direct-K exposes L2 latency: MfmaUtil 5.5%);
// V LDS-staged (R9 proved V-in-reg blows the 128-VGPR budget at 4 w/SIMD).
// Pass A: 1 barrier/kt. Pass B: 2 barriers/kt, Ps wave-private, wave-local
// coalesced NT attn write overlapping PV.
// ---------------------------------------------------------------------------
__global__ __launch_bounds__(512, 4)
void attn_kernel(const u16* __restrict__ Qw, const u16* __restrict__ Kw,
                 const u16* __restrict__ Vtw,
                 float* __restrict__ attn_out, u16* __restrict__ ctx_out) {
    __shared__ u16 H[2][128][72];   // 36864 B: pass A = K dbuf; pass B = K(H0), V(H1)
    __shared__ u16 Ps[128][136];    // 34816 B (wave-private rows in pass B)
    u16 (*Vts)[136] = (u16(*)[136])&H[1][0][0];   // 64x136 = 8704 <= 9216 u16

    const int t    = threadIdx.x;
    const int hwid = blockIdx.x + 16 * blockIdx.y;
    const int lgc  = (hwid & 7) * 64 + (hwid >> 3);
    const int bh   = lgc >> 4;
    const int q0   = (lgc & 15) * 128;
    const int w    = t >> 6;
    const int lane = t & 63;
    const int l16  = lane & 15;
    const int quad = lane >> 4;

    const u16* Qh = Qw  + (size_t)bh * SEQ * DKD;
    const u16* Kh = Kw  + (size_t)bh * SEQ * DKD;
    const u16* Vh = Vtw + (size_t)bh * DKD * SEQ;

    // Q fragments in registers: wave w owns q-rows q0 + w*16 .. +15
    bf16x8 qf[2];
#pragma unroll
    for (int ks = 0; ks < 2; ks++)
        qf[ks] = *(const bf16x8*)&Qh[(size_t)(q0 + w * 16 + l16) * 64 + ks * 32 + quad * 8];

    // staging indices: K tile 128x64 (2 chunks/thread), V tile 64x128 (2 chunks)
    const int kr0 = t >> 3,         kc0 = (t & 7) * 8;
    const int kr1 = (t + 512) >> 3, kc1 = ((t + 512) & 7) * 8;
    const int vr0 = t >> 4,         vc0 = (t & 15) * 8;
    const int vr1 = (t + 512) >> 4, vc1 = ((t + 512) & 15) * 8;

    float lsum[4];
#pragma unroll
    for (int r = 0; r < 4; r++) lsum[r] = 0.f;

    // ---------------- pass A: row denominators (m = 0), 1 barrier/kt --------
    bf16x8 kp0 = *(const bf16x8*)&Kh[(size_t)kr0 * 64 + kc0];
    bf16x8 kp1 = *(const bf16x8*)&Kh[(size_t)kr1 * 64 + kc1];
    for (int kt = 0; kt < 16; kt++) {
        u16 (*KA)[72] = H[kt & 1];
        *(bf16x8*)&KA[kr0][kc0] = kp0;
        *(bf16x8*)&KA[kr1][kc1] = kp1;
        if (kt < 15) {
            kp0 = *(const bf16x8*)&Kh[(size_t)((kt + 1) * 128 + kr0) * 64 + kc0];
            kp1 = *(const bf16x8*)&Kh[(size_t)((kt + 1) * 128 + kr1) * 64 + kc1];
        }
        __syncthreads();

        f32x4 s[8];
#pragma unroll
        for (int j = 0; j < 8; j++) { f32x4 zz = {0.f,0.f,0.f,0.f}; s[j] = zz; }
        __builtin_amdgcn_s_setprio(1);
#pragma unroll
        for (int ks = 0; ks < 2; ks++)
#pragma unroll
            for (int j = 0; j < 8; j++) {
                bf16x8 b = *(const bf16x8*)&KA[j * 16 + l16][ks * 32 + quad * 8];
                s[j] = __builtin_amdgcn_mfma_f32_16x16x32_bf16(qf[ks], b, s[j], 0, 0, 0);
            }
        __builtin_amdgcn_s_setprio(0);
#pragma unroll
        for (int j = 0; j < 8; j++)
#pragma unroll
            for (int r = 0; r < 4; r++)
                lsum[r] += exp2_hw(s[j][r]);
    }

    float lnl2[4];
#pragma unroll
    for (int r = 0; r < 4; r++) {
#pragma unroll
        for (int d = 1; d < 16; d <<= 1) lsum[r] += __shfl_xor(lsum[r], d, 64);
        lnl2[r] = log2_hw(lsum[r]);
    }

    f32x4 o[4];
#pragma unroll
    for (int jo = 0; jo < 4; jo++) { f32x4 zz = {0.f,0.f,0.f,0.f}; o[jo] = zz; }

    // ---------------- pass B: attn write + O accumulate, 2 barriers/kt ------
    kp0 = *(const bf16x8*)&Kh[(size_t)kr0 * 64 + kc0];
    kp1 = *(const bf16x8*)&Kh[(size_t)kr1 * 64 + kc1];
    bf16x8 vp0 = *(const bf16x8*)&Vh[(size_t)vr0 * 2048 + vc0];
    bf16x8 vp1 = *(const bf16x8*)&Vh[(size_t)vr1 * 2048 + vc1];
    for (int kt = 0; kt < 16; kt++) {
        __syncthreads();                 // A: prev K(H0)/V(H1) reads done
        *(bf16x8*)&H[0][kr0][kc0] = kp0;
        *(bf16x8*)&H[0][kr1][kc1] = kp1;
        *(bf16x8*)&Vts[vr0][vc0]  = vp0;
        *(bf16x8*)&Vts[vr1][vc1]  = vp1;
        if (kt < 15) {
            kp0 = *(const bf16x8*)&Kh[(size_t)((kt + 1) * 128 + kr0) * 64 + kc0];
            kp1 = *(const bf16x8*)&Kh[(size_t)((kt + 1) * 128 + kr1) * 64 + kc1];
            vp0 = *(const bf16x8*)&Vh[(size_t)vr0 * 2048 + (kt + 1) * 128 + vc0];
            vp1 = *(const bf16x8*)&Vh[(size_t)vr1 * 2048 + (kt + 1) * 128 + vc1];
        }
        __syncthreads();                 // B: K/V staged

        f32x4 s[8];
#pragma unroll
        for (int j = 0; j < 8; j++) { f32x4 zz = {0.f,0.f,0.f,0.f}; s[j] = zz; }
        __builtin_amdgcn_s_setprio(1);
#pragma unroll
        for (int ks = 0; ks < 2; ks++)
#pragma unroll
            for (int j = 0; j < 8; j++) {
                bf16x8 b = *(const bf16x8*)&H[0][j * 16 + l16][ks * 32 + quad * 8];
                s[j] = __builtin_amdgcn_mfma_f32_16x16x32_bf16(qf[ks], b, s[j], 0, 0, 0);
            }
        __builtin_amdgcn_s_setprio(0);

        // p = exp2(s - log2 l) -> Ps (bf16, wave-private rows)
#pragma unroll
        for (int j = 0; j < 8; j++)
#pragma unroll
            for (int r = 0; r < 4; r++) {
                float p = exp2_hw(s[j][r] - lnl2[r]);
                Ps[w * 16 + quad * 4 + r][j * 16 + l16] = f2bf(p);
            }

        // O += P·V (same-wave Ps rows; DS pipe in-order per wave)
        bf16x8 pa[4];
#pragma unroll
        for (int ks = 0; ks < 4; ks++)
            pa[ks] = *(const bf16x8*)&Ps[w * 16 + l16][ks * 32 + quad * 8];
        __builtin_amdgcn_s_setprio(1);
#pragma unroll
        for (int jo = 0; jo < 4; jo++)
#pragma unroll
            for (int ks = 0; ks < 4; ks++) {
                bf16x8 vb = *(const bf16x8*)&Vts[jo * 16 + l16][ks * 32 + quad * 8];
                o[jo] = __builtin_amdgcn_mfma_f32_16x16x32_bf16(pa[ks], vb, o[jo], 0, 0, 0);
            }
        __builtin_amdgcn_s_setprio(0);

        // wave-local coalesced fp32 attn write: this wave's 16 rows x 128
        // cols, f32x4/lane NT (512B contiguous per 32-lane row segment)
#pragma unroll
        for (int i = 0; i < 8; i++) {
            int cw = lane + 64 * i;            // 0..511
            int r  = cw >> 5;                  // 0..15
            int c4 = (cw & 31) * 4;            // 0..124
            bf16x4 pv = *(const bf16x4*)&Ps[w * 16 + r][c4];
            f32x4 o4;
#pragma unroll
            for (int j = 0; j < 4; j++) o4[j] = bf2f((u16)pv[j]);
            __builtin_nontemporal_store(o4,
                (f32x4*)&attn_out[((size_t)(bh * 2048 + q0 + w * 16 + r)) * 2048 + kt * 128 + c4]);
        }
    }

    // write ctx [B,S,D] bf16
    const int b = bh >> 4, h = bh & 15;
#pragma unroll
    for (int jo = 0; jo < 4; jo++)
#pragma unroll
        for (int r = 0; r < 4; r++) {
            int srow = q0 + w * 16 + quad * 4 + r;
            int dcol = h * 64 + jo * 16 + l16;
            ctx_out[((size_t)(b * 2048 + srow)) * 1024 + dcol] = f2bf(o[jo][r]);
        }
}

// ---------------------------------------------------------------------------
extern "C" void kernel_launch(void* const* d_in, const int* in_sizes, int n_in,
                              void* d_out, int out_size, void* d_ws, size_t ws_size,
                              hipStream_t stream) {
    (void)in_sizes; (void)n_in; (void)out_size; (void)ws_size;

    const float* q  = (const float*)d_in[0];
    const float* k  = (const float*)d_in[1];
    const float* v  = (const float*)d_in[2];
    const float* wq = (const float*)d_in[3];
    const float* wk = (const float*)d_in[4];
    const float* wv = (const float*)d_in[5];
    const float* wo = (const float*)d_in[6];
    const float* bo = (const float*)d_in[7];

    float* out  = (float*)d_out;                   // [2,2048,1024] fp32
    float* attn = out + (size_t)4194304;           // [2,16,2048,2048] fp32

    // workspace layout (all 4M-element granules)
    u16* Qw   = (u16*)d_ws;                        // [B,H,S,64]  bf16  8 MB
    u16* Kw   = Qw   + (size_t)4194304;            // [B,H,S,64]  bf16  8 MB
    u16* Vtw  = Kw   + (size_t)4194304;            // [B,H,64,S]  bf16  8 MB
    u16* ctxb = Vtw  + (size_t)4194304;            // [B,S,D]     bf16  8 MB
    u16* qb   = ctxb + (size_t)4194304;            // bf16 inputs 8 MB
    u16* kb   = qb   + (size_t)4194304;            //             8 MB
    u16* vb   = kb   + (size_t)4194304;            //             8 MB
    u16* wb   = vb   + (size_t)4194304;            // wq|wk|wv|wo 8 MB

    dim3 blk(256);
    cast_all<<<dim3(512, 16), blk, 0, stream>>>(q, k, v, wq, wk, wv, wo,
                                                qb, kb, vb, wb);
    qkv_gemm<<<dim3(8, 32, 3), blk, 0, stream>>>(qb, kb, vb, wb, Qw, Kw, Vtw);
    attn_kernel<<<dim3(16, 32), dim3(512), 0, stream>>>(Qw, Kw, Vtw, attn, ctxb);
    out_gemm<<<dim3(16, 32), blk, 0, stream>>>(ctxb, wb + (size_t)3 * 1048576, out, bo);
}